// Round 1
// baseline (233.077 us; speedup 1.0000x reference)
//
#include <hip/hip_runtime.h>
#include <hip/hip_bf16.h>
#include <math.h>

#define HDIM 150   // hidden width layers 1 & 3
#define PDIM 8     // layer-2 output channels
#define MREADS 32  // reads per site
#define R1 2       // reads per thread in kernel 1

// ---------------------------------------------------------------------------
// Kernel 1: per-read MLP   h = relu(relu([x, emb[kmer]] @ W1 + b1) @ W2 + b2)
// x: [N,16] f32, kmer: [N] i32, emb: [18,2], W1: [18,150], W2: [150,8]
// writes h: [N,8] f32 into workspace
// ---------------------------------------------------------------------------
__global__ __launch_bounds__(256) void k_readmlp(
    const float* __restrict__ x, const int* __restrict__ kmer,
    const float* __restrict__ emb, const float* __restrict__ W1,
    const float* __restrict__ b1, const float* __restrict__ W2,
    const float* __restrict__ b2, float* __restrict__ h, int Ntot)
{
    // W1 transposed: row j holds the 18 weights feeding hidden unit j.
    // pitch 20 floats (80 B) keeps every row 16B-aligned for b128 reads.
    __shared__ float sW1[HDIM * 20];
    __shared__ float sW2[HDIM * 8];
    __shared__ float sB1[HDIM];

    const int tid = threadIdx.x;
    for (int e = tid; e < 18 * HDIM; e += 256) {
        int k = e / HDIM, j = e - k * HDIM;      // W1 is [18][150] row-major
        sW1[j * 20 + k] = W1[e];
    }
    for (int e = tid; e < HDIM * 8; e += 256) sW2[e] = W2[e];
    for (int e = tid; e < HDIM; e += 256) sB1[e] = b1[e];

    float bb2[8];
#pragma unroll
    for (int p = 0; p < 8; ++p) bb2[p] = b2[p];
    __syncthreads();

    const int base = blockIdx.x * (256 * R1) + tid;

    float in[R1][18];
    float acc[R1][8];
    bool ok[R1];
#pragma unroll
    for (int rr = 0; rr < R1; ++rr) {
        int r = base + rr * 256;
        ok[rr] = (r < Ntot);
        int rs = ok[rr] ? r : 0;
        const float4* xr = (const float4*)(x + (size_t)rs * 16);
        float4 a0 = xr[0], a1 = xr[1], a2 = xr[2], a3 = xr[3];
        in[rr][0] = a0.x; in[rr][1] = a0.y; in[rr][2]  = a0.z; in[rr][3]  = a0.w;
        in[rr][4] = a1.x; in[rr][5] = a1.y; in[rr][6]  = a1.z; in[rr][7]  = a1.w;
        in[rr][8] = a2.x; in[rr][9] = a2.y; in[rr][10] = a2.z; in[rr][11] = a2.w;
        in[rr][12] = a3.x; in[rr][13] = a3.y; in[rr][14] = a3.z; in[rr][15] = a3.w;
        int km = kmer[rs];
        float2 e2 = ((const float2*)emb)[km];
        in[rr][16] = e2.x; in[rr][17] = e2.y;
#pragma unroll
        for (int p = 0; p < 8; ++p) acc[rr][p] = bb2[p];
    }

    for (int j = 0; j < HDIM; ++j) {
        const float4* wr4 = (const float4*)(sW1 + j * 20);
        float4 t0 = wr4[0], t1 = wr4[1], t2 = wr4[2], t3 = wr4[3];
        float2 t4 = *(const float2*)(sW1 + j * 20 + 16);
        float w[18];
        w[0] = t0.x; w[1] = t0.y; w[2]  = t0.z; w[3]  = t0.w;
        w[4] = t1.x; w[5] = t1.y; w[6]  = t1.z; w[7]  = t1.w;
        w[8] = t2.x; w[9] = t2.y; w[10] = t2.z; w[11] = t2.w;
        w[12] = t3.x; w[13] = t3.y; w[14] = t3.z; w[15] = t3.w;
        w[16] = t4.x; w[17] = t4.y;
        float bj = sB1[j];
        const float4* u4 = (const float4*)(sW2 + j * 8);
        float4 u0 = u4[0], u1 = u4[1];
#pragma unroll
        for (int rr = 0; rr < R1; ++rr) {
            float a = bj;
#pragma unroll
            for (int k = 0; k < 18; ++k) a = fmaf(in[rr][k], w[k], a);
            a = fmaxf(a, 0.f);
            acc[rr][0] = fmaf(a, u0.x, acc[rr][0]);
            acc[rr][1] = fmaf(a, u0.y, acc[rr][1]);
            acc[rr][2] = fmaf(a, u0.z, acc[rr][2]);
            acc[rr][3] = fmaf(a, u0.w, acc[rr][3]);
            acc[rr][4] = fmaf(a, u1.x, acc[rr][4]);
            acc[rr][5] = fmaf(a, u1.y, acc[rr][5]);
            acc[rr][6] = fmaf(a, u1.z, acc[rr][6]);
            acc[rr][7] = fmaf(a, u1.w, acc[rr][7]);
        }
    }

#pragma unroll
    for (int rr = 0; rr < R1; ++rr) {
        int r = base + rr * 256;
        if (!ok[rr]) continue;
        float4* hp = (float4*)(h + (size_t)r * 8);
        float4 o0, o1;
        o0.x = fmaxf(acc[rr][0], 0.f); o0.y = fmaxf(acc[rr][1], 0.f);
        o0.z = fmaxf(acc[rr][2], 0.f); o0.w = fmaxf(acc[rr][3], 0.f);
        o1.x = fmaxf(acc[rr][4], 0.f); o1.y = fmaxf(acc[rr][5], 0.f);
        o1.z = fmaxf(acc[rr][6], 0.f); o1.w = fmaxf(acc[rr][7], 0.f);
        hp[0] = o0; hp[1] = o1;
    }
}

// ---------------------------------------------------------------------------
// compare-exchange + fully unrolled Batcher odd-even mergesort, n = 32
// ---------------------------------------------------------------------------
__device__ __forceinline__ void cswap(float& a, float& b) {
    float lo = fminf(a, b);
    float hi = fmaxf(a, b);
    a = lo; b = hi;
}

__device__ __forceinline__ void sort32(float v[32]) {
#pragma unroll
    for (int pp = 1; pp < 32; pp <<= 1) {
#pragma unroll
        for (int k = pp; k >= 1; k >>= 1) {
#pragma unroll
            for (int j = k & (pp - 1); j + k < 32; j += 2 * k) {
#pragma unroll
                for (int i = 0; i < k; ++i) {
                    if ((i + j) / (2 * pp) == (i + j + k) / (2 * pp))
                        cswap(v[i + j], v[i + j + k]);
                }
            }
        }
    }
}

// ---------------------------------------------------------------------------
// Kernel 2: per-site aggregation + head MLP
// thread layout: tid = g*8 + p  (32 groups/block, 8 channels)
// ---------------------------------------------------------------------------
__global__ __launch_bounds__(256) void k_site(
    const float* __restrict__ h, const int* __restrict__ indices,
    const float* __restrict__ W3, const float* __restrict__ b3,
    const float* __restrict__ W4, const float* __restrict__ b4,
    float* __restrict__ out, int Gtot)
{
    __shared__ int   sIdx[32 * 33];       // pitch 33 -> conflict-free reads
    __shared__ float sAgg[32 * 41];       // [group][40] pitch 41
    __shared__ float sW3[HDIM * 41];      // W3 transposed: [j][40] pitch 41
    __shared__ float sB3[HDIM];
    __shared__ float sW4[HDIM];

    const int tid  = threadIdx.x;
    const int gblk = blockIdx.x * 32;

    for (int e = tid; e < 32 * MREADS; e += 256) {
        int g = e >> 5, m = e & 31;
        int src = gblk * MREADS + e;
        sIdx[g * 33 + m] = (gblk + g < Gtot) ? indices[src] : 0;
    }
    for (int e = tid; e < 40 * HDIM; e += 256) {
        int c = e / HDIM, j = e - c * HDIM;   // W3 is [40][150] row-major
        sW3[j * 41 + c] = W3[e];
    }
    for (int e = tid; e < HDIM; e += 256) { sB3[e] = b3[e]; sW4[e] = W4[e]; }
    __syncthreads();

    const int g = tid >> 3;
    const int p = tid & 7;
    const bool gok = (gblk + g) < Gtot;

    // gather the 32 values of this (group, channel)
    float v[32];
#pragma unroll
    for (int m = 0; m < MREADS; ++m) {
        int r = sIdx[g * 33 + m];
        v[m] = h[(size_t)r * 8 + p];
    }

    // stats
    float sum = 0.f, sumsq = 0.f, mn = v[0], mx = v[0];
#pragma unroll
    for (int m = 0; m < MREADS; ++m) {
        sum += v[m];
        sumsq = fmaf(v[m], v[m], sumsq);
        mn = fminf(mn, v[m]);
        mx = fmaxf(mx, v[m]);
    }
    float mean = sum * (1.f / 32.f);
    float var  = fmaxf((sumsq - 32.f * mean * mean) * (1.f / 31.f), 0.f);

    sort32(v);
    float med = v[15];   // lower median, index (32-1)//2

    sAgg[g * 41 + 0 * 8 + p] = mean;
    sAgg[g * 41 + 1 * 8 + p] = var;
    sAgg[g * 41 + 2 * 8 + p] = mn;
    sAgg[g * 41 + 3 * 8 + p] = med;
    sAgg[g * 41 + 4 * 8 + p] = mx;
    __syncthreads();

    // head: z = relu(agg @ W3 + b3); out = sigmoid(z . W4 + b4)
    float ag[40];
#pragma unroll
    for (int c = 0; c < 40; ++c) ag[c] = sAgg[g * 41 + c];

    float acc = 0.f;
    for (int j = p; j < HDIM; j += 8) {
        float z = sB3[j];
        const float* wr = sW3 + j * 41;
#pragma unroll
        for (int c = 0; c < 40; ++c) z = fmaf(ag[c], wr[c], z);
        z = fmaxf(z, 0.f);
        acc = fmaf(z, sW4[j], acc);
    }
    acc += __shfl_xor(acc, 1);
    acc += __shfl_xor(acc, 2);
    acc += __shfl_xor(acc, 4);

    if (p == 0 && gok) {
        float zf = acc + b4[0];
        out[gblk + g] = 1.f / (1.f + expf(-zf));
    }
}

// ---------------------------------------------------------------------------
extern "C" void kernel_launch(void* const* d_in, const int* in_sizes, int n_in,
                              void* d_out, int out_size, void* d_ws, size_t ws_size,
                              hipStream_t stream) {
    const float* x       = (const float*)d_in[0];
    const int*   kmer    = (const int*)  d_in[1];
    const int*   indices = (const int*)  d_in[2];
    const float* emb     = (const float*)d_in[3];
    const float* W1      = (const float*)d_in[4];
    const float* b1      = (const float*)d_in[5];
    const float* W2      = (const float*)d_in[6];
    const float* b2      = (const float*)d_in[7];
    const float* W3      = (const float*)d_in[8];
    const float* b3      = (const float*)d_in[9];
    const float* W4      = (const float*)d_in[10];
    const float* b4      = (const float*)d_in[11];

    float* out = (float*)d_out;
    float* h   = (float*)d_ws;            // [N, 8] f32 = 32 MB

    const int N = in_sizes[1];            // kmer count
    const int G = out_size;               // sites

    const int grid1 = (N + 256 * R1 - 1) / (256 * R1);
    k_readmlp<<<grid1, 256, 0, stream>>>(x, kmer, emb, W1, b1, W2, b2, h, N);

    const int grid2 = (G + 31) / 32;
    k_site<<<grid2, 256, 0, stream>>>(h, indices, W3, b3, W4, b4, out, G);
}

// Round 2
// 176.492 us; speedup vs baseline: 1.3206x; 1.3206x over previous
//
#include <hip/hip_runtime.h>
#include <hip/hip_bf16.h>
#include <math.h>

#define HDIM 150
#define H1PITCH 192   // bf16 elems per h1 row in LDS (160 used + swizzle pad to 24x 16B units)

typedef __bf16 bf16x8 __attribute__((ext_vector_type(8)));
typedef __bf16 bf16x4 __attribute__((ext_vector_type(4)));
typedef float  f32x4  __attribute__((ext_vector_type(4)));

// ---------------------------------------------------------------------------
// Kernel 1: per-read MLP via bf16 MFMA, transposed tiles.
//   Layer1: D1[hidden][read] = mfma(A=W1^T tile, B=input frag)   10 n-tiles
//   Layer2: D2[p][read]      = mfma(A=W2^T tile, B=h1 from LDS)  5 k-tiles
// h written as bf16 [N,8].
// ---------------------------------------------------------------------------
__global__ __launch_bounds__(256, 4) void k_readmlp(
    const float* __restrict__ x, const int* __restrict__ kmer,
    const float* __restrict__ emb, const float* __restrict__ W1,
    const float* __restrict__ b1, const float* __restrict__ W2,
    const float* __restrict__ b2, __bf16* __restrict__ h, int Ntot)
{
    // staging area (4050 f32) then 4 wave-private h1 tiles (4 x 16 x 192 bf16)
    __shared__ float smemF[6144];

    const int tid  = threadIdx.x;
    const int lane = tid & 63;
    const int wv   = tid >> 6;
    const int m    = lane & 15;   // B-col (read) / A-row index
    const int q    = lane >> 4;   // quad
    const int sw   = m & 7;       // LDS swizzle key

    // ---- stage raw weights to LDS (coalesced) ----
    for (int e = tid; e < 2700; e += 256) smemF[e] = W1[e];          // [18][150]
    for (int e = tid; e < 150;  e += 256) smemF[2700 + e] = b1[e];
    for (int e = tid; e < 1200; e += 256) smemF[2850 + e] = W2[e];   // [150][8]
    __syncthreads();

    // ---- build resident A-fragments in VGPRs ----
    // layer1 A[m=hidden][k=input-dim]; k==18 row = b1 (input supplies 1.0)
    bf16x8 fA1[10];
#pragma unroll
    for (int n = 0; n < 10; ++n) {
        int hid = n * 16 + m;
#pragma unroll
        for (int j = 0; j < 8; ++j) {
            int k = q * 8 + j;
            float v = 0.f;
            if (hid < HDIM) {
                if (k < 18)       v = smemF[k * HDIM + hid];
                else if (k == 18) v = smemF[2700 + hid];
            }
            fA1[n][j] = (__bf16)v;
        }
    }
    // layer2 A[m=p][k=hidden]; rows p>=8 and k>=150 are zero
    bf16x8 fA2[5];
#pragma unroll
    for (int kt = 0; kt < 5; ++kt) {
#pragma unroll
        for (int j = 0; j < 8; ++j) {
            int k = kt * 32 + q * 8 + j;
            float v = 0.f;
            if (m < 8 && k < HDIM) v = smemF[2850 + k * 8 + m];
            fA2[kt][j] = (__bf16)v;
        }
    }
    float4 breg = *(const float4*)(b2 + (q & 1) * 4);   // b2[q*4..q*4+3] for q<2
    __syncthreads();   // smemF now reused as h1 tiles

    __bf16* hbase = ((__bf16*)smemF) + wv * (16 * H1PITCH);
    const float4* x4   = (const float4*)x;
    const float2* emb2 = (const float2*)emb;

    const int waveBase = blockIdx.x * 1024 + wv * 256;
    const f32x4 zero = {0.f, 0.f, 0.f, 0.f};

    for (int t = 0; t < 16; ++t) {
        int rbase = waveBase + t * 16;
        if (rbase >= Ntot) break;           // wave-uniform
        int r  = rbase + m;
        int rc = r < Ntot ? r : (Ntot - 1);

        // ---- input B-fragment: B[k = q*8+j][n = read m] ----
        bf16x8 bin;
        if (q < 2) {
            float4 u0 = x4[(size_t)rc * 4 + q * 2];
            float4 u1 = x4[(size_t)rc * 4 + q * 2 + 1];
            bin[0] = (__bf16)u0.x; bin[1] = (__bf16)u0.y;
            bin[2] = (__bf16)u0.z; bin[3] = (__bf16)u0.w;
            bin[4] = (__bf16)u1.x; bin[5] = (__bf16)u1.y;
            bin[6] = (__bf16)u1.z; bin[7] = (__bf16)u1.w;
        } else if (q == 2) {
            float2 e2 = emb2[kmer[rc]];
            bin[0] = (__bf16)e2.x; bin[1] = (__bf16)e2.y;
            bin[2] = (__bf16)1.0f;   // k==18: bias-1 input
            bin[3] = (__bf16)0.f; bin[4] = (__bf16)0.f;
            bin[5] = (__bf16)0.f; bin[6] = (__bf16)0.f; bin[7] = (__bf16)0.f;
        } else {
#pragma unroll
            for (int j = 0; j < 8; ++j) bin[j] = (__bf16)0.f;
        }

        // ---- layer 1 in two halves (keeps C1 at 20 VGPRs) ----
        // lane holds D1[row = hidden q*4+reg][col = read m]
#define EPI1(cc, nn) { \
            bf16x4 pk; \
            pk[0] = (__bf16)fmaxf((cc)[0], 0.f); \
            pk[1] = (__bf16)fmaxf((cc)[1], 0.f); \
            pk[2] = (__bf16)fmaxf((cc)[2], 0.f); \
            pk[3] = (__bf16)fmaxf((cc)[3], 0.f); \
            int u = (nn) * 2 + (q >> 1); \
            int off = m * H1PITCH + ((u ^ sw) << 3) + (q & 1) * 4; \
            *(bf16x4*)(hbase + off) = pk; }

        f32x4 c1[5];
#pragma unroll
        for (int n = 0; n < 5; ++n)
            c1[n] = __builtin_amdgcn_mfma_f32_16x16x32_bf16(fA1[n], bin, zero, 0, 0, 0);
#pragma unroll
        for (int n = 0; n < 5; ++n) EPI1(c1[n], n)
#pragma unroll
        for (int n = 0; n < 5; ++n)
            c1[n] = __builtin_amdgcn_mfma_f32_16x16x32_bf16(fA1[n + 5], bin, zero, 0, 0, 0);
#pragma unroll
        for (int n = 0; n < 5; ++n) EPI1(c1[n], n + 5)
#undef EPI1

        // ---- layer 2: B2[k][read] from swizzled LDS, accumulate over kt ----
        f32x4 c2 = zero;
#pragma unroll
        for (int kt = 0; kt < 5; ++kt) {
            int u = kt * 4 + q;
            int off = m * H1PITCH + ((u ^ sw) << 3);
            bf16x8 bf = *(bf16x8*)(hbase + off);
            c2 = __builtin_amdgcn_mfma_f32_16x16x32_bf16(fA2[kt], bf, c2, 0, 0, 0);
        }

        // lane holds D2[row = p = q*4+reg][col = read m]; only q<2 rows real
        if (q < 2 && r < Ntot) {
            bf16x4 o;
            o[0] = (__bf16)fmaxf(c2[0] + breg.x, 0.f);
            o[1] = (__bf16)fmaxf(c2[1] + breg.y, 0.f);
            o[2] = (__bf16)fmaxf(c2[2] + breg.z, 0.f);
            o[3] = (__bf16)fmaxf(c2[3] + breg.w, 0.f);
            *(bf16x4*)(h + (size_t)r * 8 + q * 4) = o;   // coalesced dwordx2
        }
    }
}

// ---------------------------------------------------------------------------
// fully unrolled Batcher odd-even mergesort, n = 32
// ---------------------------------------------------------------------------
__device__ __forceinline__ void cswap(float& a, float& b) {
    float lo = fminf(a, b);
    float hi = fmaxf(a, b);
    a = lo; b = hi;
}

__device__ __forceinline__ void sort32(float v[32]) {
#pragma unroll
    for (int pp = 1; pp < 32; pp <<= 1) {
#pragma unroll
        for (int k = pp; k >= 1; k >>= 1) {
#pragma unroll
            for (int j = k & (pp - 1); j + k < 32; j += 2 * k) {
#pragma unroll
                for (int i = 0; i < k; ++i) {
                    if ((i + j) / (2 * pp) == (i + j + k) / (2 * pp))
                        cswap(v[i + j], v[i + j + k]);
                }
            }
        }
    }
}

// ---------------------------------------------------------------------------
// Kernel 2: per-site aggregation + head MLP
// Phase 1: thread=(g,p): gather 32 bf16, stats+sort -> sAgg
// Phase 2: 4 waves, lane=group, strided j, weights via wave-uniform s_loads
// ---------------------------------------------------------------------------
__global__ __launch_bounds__(256) void k_site(
    const __bf16* __restrict__ hb, const int* __restrict__ indices,
    const float* __restrict__ W3, const float* __restrict__ b3,
    const float* __restrict__ W4, const float* __restrict__ b4,
    float* __restrict__ out, int Gtot)
{
    __shared__ int   sIdx[32 * 33];
    __shared__ float sAgg[32 * 41];
    __shared__ float sPart[128];

    const int tid  = threadIdx.x;
    const int gblk = blockIdx.x * 32;

    for (int e = tid; e < 32 * 32; e += 256) {
        int g = e >> 5;
        sIdx[g * 33 + (e & 31)] = (gblk + g < Gtot) ? indices[gblk * 32 + e] : 0;
    }
    __syncthreads();

    {
        const int g = tid >> 3, p = tid & 7;
        float v[32];
#pragma unroll
        for (int mm = 0; mm < 32; ++mm) {
            int r = sIdx[g * 33 + mm];
            v[mm] = (float)hb[(size_t)r * 8 + p];
        }
        float sum = 0.f, sumsq = 0.f, mn = v[0], mx = v[0];
#pragma unroll
        for (int mm = 0; mm < 32; ++mm) {
            sum += v[mm];
            sumsq = fmaf(v[mm], v[mm], sumsq);
            mn = fminf(mn, v[mm]);
            mx = fmaxf(mx, v[mm]);
        }
        float mean = sum * (1.f / 32.f);
        float var  = fmaxf((sumsq - 32.f * mean * mean) * (1.f / 31.f), 0.f);
        sort32(v);
        sAgg[g * 41 + 0 * 8 + p] = mean;
        sAgg[g * 41 + 1 * 8 + p] = var;
        sAgg[g * 41 + 2 * 8 + p] = mn;
        sAgg[g * 41 + 3 * 8 + p] = v[15];   // lower median
        sAgg[g * 41 + 4 * 8 + p] = mx;
    }
    __syncthreads();

    {
        const int w    = __builtin_amdgcn_readfirstlane(tid >> 6);
        const int lane = tid & 63;
        if (lane < 32) {
            float ag[40];
#pragma unroll
            for (int c = 0; c < 40; ++c) ag[c] = sAgg[lane * 41 + c];  // conflict-free (9g bijective mod 32)
            float acc = 0.f;
            for (int j = w; j < HDIM; j += 4) {     // j wave-uniform -> W3/b3/W4 via s_load
                float z = b3[j];
#pragma unroll
                for (int c = 0; c < 40; ++c) z = fmaf(ag[c], W3[c * HDIM + j], z);
                z = fmaxf(z, 0.f);
                acc = fmaf(z, W4[j], acc);
            }
            sPart[w * 32 + lane] = acc;
        }
    }
    __syncthreads();

    if (tid < 32 && gblk + tid < Gtot) {
        float s = sPart[tid] + sPart[32 + tid] + sPart[64 + tid] + sPart[96 + tid] + b4[0];
        out[gblk + tid] = 1.f / (1.f + expf(-s));
    }
}

// ---------------------------------------------------------------------------
extern "C" void kernel_launch(void* const* d_in, const int* in_sizes, int n_in,
                              void* d_out, int out_size, void* d_ws, size_t ws_size,
                              hipStream_t stream) {
    const float* x       = (const float*)d_in[0];
    const int*   kmer    = (const int*)  d_in[1];
    const int*   indices = (const int*)  d_in[2];
    const float* emb     = (const float*)d_in[3];
    const float* W1      = (const float*)d_in[4];
    const float* b1      = (const float*)d_in[5];
    const float* W2      = (const float*)d_in[6];
    const float* b2      = (const float*)d_in[7];
    const float* W3      = (const float*)d_in[8];
    const float* b3      = (const float*)d_in[9];
    const float* W4      = (const float*)d_in[10];
    const float* b4      = (const float*)d_in[11];

    float*  out = (float*)d_out;
    __bf16* h   = (__bf16*)d_ws;          // [N, 8] bf16 = 16 MB

    const int N = in_sizes[1];            // reads
    const int G = out_size;               // sites

    const int grid1 = (N + 1023) / 1024;  // 1024 reads per block (4 waves x 256)
    k_readmlp<<<grid1, 256, 0, stream>>>(x, kmer, emb, W1, b1, W2, b2, h, N);

    const int grid2 = (G + 31) / 32;
    k_site<<<grid2, 256, 0, stream>>>(h, indices, W3, b3, W4, b4, out, G);
}

// Round 3
// 175.265 us; speedup vs baseline: 1.3299x; 1.0070x over previous
//
#include <hip/hip_runtime.h>
#include <hip/hip_bf16.h>
#include <math.h>

#define HDIM 150

typedef __bf16 bf16x8 __attribute__((ext_vector_type(8)));
typedef __bf16 bf16x4 __attribute__((ext_vector_type(4)));
typedef float  f32x4  __attribute__((ext_vector_type(4)));

// ---------------------------------------------------------------------------
// Kernel 1: per-read MLP via bf16 MFMA with register-relay layer1->layer2.
// Hidden units are PERMUTED across layer-1 A-tiles so that the packed C/D
// output of tile pair (2kt, 2kt+1) is exactly the layer-2 B-fragment for kt:
//   tile 2kt   row (4q+r) = hidden 32kt+8q+r     (j=0..3 of B2)
//   tile 2kt+1 row (4q+r) = hidden 32kt+8q+4+r   (j=4..7 of B2)
// => no LDS / no shuffles in the main loop. fA2's logical k-order unchanged.
// ---------------------------------------------------------------------------
__global__ __launch_bounds__(256, 4) void k_readmlp(
    const float* __restrict__ x, const int* __restrict__ kmer,
    const float* __restrict__ emb, const float* __restrict__ W1,
    const float* __restrict__ b1, const float* __restrict__ W2,
    const float* __restrict__ b2, __bf16* __restrict__ h, int Ntot)
{
    __shared__ float sW[4050];   // W1 [18][150] | b1 @2700 | W2 [150][8] @2850

    const int tid  = threadIdx.x;
    const int lane = tid & 63;
    const int wv   = tid >> 6;
    const int m    = lane & 15;
    const int q    = lane >> 4;

    for (int e = tid; e < 2700; e += 256) sW[e] = W1[e];
    for (int e = tid; e < 150;  e += 256) sW[2700 + e] = b1[e];
    for (int e = tid; e < 1200; e += 256) sW[2850 + e] = W2[e];
    __syncthreads();

    // layer-1 A-fragments with permuted hidden rows; k==18 row carries b1.
    bf16x8 fA1[10];
#pragma unroll
    for (int n = 0; n < 10; ++n) {
        int hid = 32 * (n >> 1) + 8 * (m >> 2) + 4 * (n & 1) + (m & 3);
#pragma unroll
        for (int j = 0; j < 8; ++j) {
            int k = q * 8 + j;
            float v = 0.f;
            if (hid < HDIM) {
                if (k < 18)       v = sW[k * HDIM + hid];
                else if (k == 18) v = sW[2700 + hid];
            }
            fA1[n][j] = (__bf16)v;
        }
    }
    // layer-2 A: A2[m=p][k=hidden logical], rows m>=8 and k>=150 zero.
    bf16x8 fA2[5];
#pragma unroll
    for (int kt = 0; kt < 5; ++kt) {
#pragma unroll
        for (int j = 0; j < 8; ++j) {
            int k = kt * 32 + q * 8 + j;
            float v = 0.f;
            if (m < 8 && k < HDIM) v = sW[2850 + k * 8 + m];
            fA2[kt][j] = (__bf16)v;
        }
    }
    float4 breg = *(const float4*)(b2 + (q & 1) * 4);

    const float4* x4   = (const float4*)x;
    const float2* emb2 = (const float2*)emb;
    const int waveBase = blockIdx.x * 1024 + wv * 256;
    const f32x4 zero = {0.f, 0.f, 0.f, 0.f};

    // prefetch t = 0
    float4 cx0, cx1; int ckm = 0;
    {
        int r  = waveBase + m;
        int rc = r < Ntot ? r : (Ntot - 1);
        if (q < 2) {
            cx0 = x4[(size_t)rc * 4 + q * 2];
            cx1 = x4[(size_t)rc * 4 + q * 2 + 1];
        } else if (q == 2) {
            ckm = kmer[rc];
        }
    }

    for (int t = 0; t < 16; ++t) {
        // prefetch t+1 (no barriers anywhere -> loads pipeline deep)
        float4 nx0 = cx0, nx1 = cx1; int nkm = ckm;
        if (t < 15) {
            int r  = waveBase + (t + 1) * 16 + m;
            int rc = r < Ntot ? r : (Ntot - 1);
            if (q < 2) {
                nx0 = x4[(size_t)rc * 4 + q * 2];
                nx1 = x4[(size_t)rc * 4 + q * 2 + 1];
            } else if (q == 2) {
                nkm = kmer[rc];
            }
        }

        // build input B-fragment from current prefetch
        bf16x8 bin;
        if (q < 2) {
            bin[0] = (__bf16)cx0.x; bin[1] = (__bf16)cx0.y;
            bin[2] = (__bf16)cx0.z; bin[3] = (__bf16)cx0.w;
            bin[4] = (__bf16)cx1.x; bin[5] = (__bf16)cx1.y;
            bin[6] = (__bf16)cx1.z; bin[7] = (__bf16)cx1.w;
        } else if (q == 2) {
            float2 e2 = emb2[ckm];
            bin[0] = (__bf16)e2.x; bin[1] = (__bf16)e2.y;
            bin[2] = (__bf16)1.0f;   // bias-1 input at k==18
            bin[3] = (__bf16)0.f; bin[4] = (__bf16)0.f;
            bin[5] = (__bf16)0.f; bin[6] = (__bf16)0.f; bin[7] = (__bf16)0.f;
        } else {
#pragma unroll
            for (int j = 0; j < 8; ++j) bin[j] = (__bf16)0.f;
        }

        // layer1 tile-pair -> relu/pack -> layer2, all in registers
        f32x4 c2 = zero;
#pragma unroll
        for (int kt = 0; kt < 5; ++kt) {
            f32x4 ca = __builtin_amdgcn_mfma_f32_16x16x32_bf16(fA1[2 * kt],     bin, zero, 0, 0, 0);
            f32x4 cb = __builtin_amdgcn_mfma_f32_16x16x32_bf16(fA1[2 * kt + 1], bin, zero, 0, 0, 0);
            bf16x8 bh;
            bh[0] = (__bf16)fmaxf(ca[0], 0.f); bh[1] = (__bf16)fmaxf(ca[1], 0.f);
            bh[2] = (__bf16)fmaxf(ca[2], 0.f); bh[3] = (__bf16)fmaxf(ca[3], 0.f);
            bh[4] = (__bf16)fmaxf(cb[0], 0.f); bh[5] = (__bf16)fmaxf(cb[1], 0.f);
            bh[6] = (__bf16)fmaxf(cb[2], 0.f); bh[7] = (__bf16)fmaxf(cb[3], 0.f);
            c2 = __builtin_amdgcn_mfma_f32_16x16x32_bf16(fA2[kt], bh, c2, 0, 0, 0);
        }

        int r = waveBase + t * 16 + m;
        if (q < 2 && r < Ntot) {
            bf16x4 o;
            o[0] = (__bf16)fmaxf(c2[0] + breg.x, 0.f);
            o[1] = (__bf16)fmaxf(c2[1] + breg.y, 0.f);
            o[2] = (__bf16)fmaxf(c2[2] + breg.z, 0.f);
            o[3] = (__bf16)fmaxf(c2[3] + breg.w, 0.f);
            *(bf16x4*)(h + (size_t)r * 8 + q * 4) = o;
        }
        cx0 = nx0; cx1 = nx1; ckm = nkm;
    }
}

// ---------------------------------------------------------------------------
// fully unrolled Batcher odd-even mergesort, n = 32
// ---------------------------------------------------------------------------
__device__ __forceinline__ void cswap(float& a, float& b) {
    float lo = fminf(a, b);
    float hi = fmaxf(a, b);
    a = lo; b = hi;
}

__device__ __forceinline__ void sort32(float v[32]) {
#pragma unroll
    for (int pp = 1; pp < 32; pp <<= 1) {
#pragma unroll
        for (int k = pp; k >= 1; k >>= 1) {
#pragma unroll
            for (int j = k & (pp - 1); j + k < 32; j += 2 * k) {
#pragma unroll
                for (int i = 0; i < k; ++i) {
                    if ((i + j) / (2 * pp) == (i + j + k) / (2 * pp))
                        cswap(v[i + j], v[i + j + k]);
                }
            }
        }
    }
}

// ---------------------------------------------------------------------------
// Kernel 2: per-site aggregation + head MLP.
// Phase 1: thread=(g,p): gather 32 bf16, stats + sort -> sAgg (f32).
// Phase 2: thread=(g,p): j = p..150 step 8; W3^T in LDS pitch 44
//          (16B-aligned rows, 12p%32 distinct banks -> conflict-free b128).
// ---------------------------------------------------------------------------
__global__ __launch_bounds__(256) void k_site(
    const __bf16* __restrict__ hb, const int* __restrict__ indices,
    const float* __restrict__ W3, const float* __restrict__ b3,
    const float* __restrict__ W4, const float* __restrict__ b4,
    float* __restrict__ out, int Gtot)
{
    __shared__ int   sIdx[32 * 33];     // 4.2 KB
    __shared__ float sW3T[HDIM * 44];   // 26.4 KB, row j = W3[:,j], pitch 44
    __shared__ float sB3[HDIM];
    __shared__ float sW4[HDIM];
    __shared__ float sAgg[32 * 44];     // 5.6 KB, [group][40] pitch 44

    const int tid  = threadIdx.x;
    const int gblk = blockIdx.x * 32;

    for (int e = tid; e < 1024; e += 256) {
        int g = e >> 5;
        sIdx[g * 33 + (e & 31)] = (gblk + g < Gtot) ? indices[(size_t)gblk * 32 + e] : 0;
    }
    for (int e = tid; e < 40 * HDIM; e += 256) {
        int c = e / HDIM, j = e - c * HDIM;    // W3 row-major [40][150]
        sW3T[j * 44 + c] = W3[e];
    }
    for (int e = tid; e < HDIM; e += 256) { sB3[e] = b3[e]; sW4[e] = W4[e]; }
    __syncthreads();

    const int g = tid >> 3, p = tid & 7;
    {
        float v[32];
#pragma unroll
        for (int mm = 0; mm < 32; ++mm) {
            int r = sIdx[g * 33 + mm];
            v[mm] = (float)hb[(size_t)r * 8 + p];
        }
        float sum = 0.f, sumsq = 0.f, mn = v[0], mx = v[0];
#pragma unroll
        for (int mm = 0; mm < 32; ++mm) {
            sum += v[mm];
            sumsq = fmaf(v[mm], v[mm], sumsq);
            mn = fminf(mn, v[mm]);
            mx = fmaxf(mx, v[mm]);
        }
        float mean = sum * (1.f / 32.f);
        float var  = fmaxf((sumsq - 32.f * mean * mean) * (1.f / 31.f), 0.f);
        sort32(v);
        sAgg[g * 44 + 0 * 8 + p] = mean;
        sAgg[g * 44 + 1 * 8 + p] = var;
        sAgg[g * 44 + 2 * 8 + p] = mn;
        sAgg[g * 44 + 3 * 8 + p] = v[15];   // lower median
        sAgg[g * 44 + 4 * 8 + p] = mx;
    }
    __syncthreads();

    float ag[40];
#pragma unroll
    for (int c4 = 0; c4 < 10; ++c4) {
        float4 tq = *(const float4*)(sAgg + g * 44 + c4 * 4);
        ag[c4 * 4 + 0] = tq.x; ag[c4 * 4 + 1] = tq.y;
        ag[c4 * 4 + 2] = tq.z; ag[c4 * 4 + 3] = tq.w;
    }

    float acc = 0.f;
    for (int j = p; j < HDIM; j += 8) {
        const float* wr = sW3T + j * 44;
        float z = sB3[j];
#pragma unroll
        for (int c4 = 0; c4 < 10; ++c4) {
            float4 w = *(const float4*)(wr + c4 * 4);
            z = fmaf(ag[c4 * 4 + 0], w.x, z);
            z = fmaf(ag[c4 * 4 + 1], w.y, z);
            z = fmaf(ag[c4 * 4 + 2], w.z, z);
            z = fmaf(ag[c4 * 4 + 3], w.w, z);
        }
        z = fmaxf(z, 0.f);
        acc = fmaf(z, sW4[j], acc);
    }
    acc += __shfl_xor(acc, 1);
    acc += __shfl_xor(acc, 2);
    acc += __shfl_xor(acc, 4);

    if (p == 0 && gblk + g < Gtot) {
        float zf = acc + b4[0];
        out[gblk + g] = 1.f / (1.f + expf(-zf));
    }
}

// ---------------------------------------------------------------------------
extern "C" void kernel_launch(void* const* d_in, const int* in_sizes, int n_in,
                              void* d_out, int out_size, void* d_ws, size_t ws_size,
                              hipStream_t stream) {
    const float* x       = (const float*)d_in[0];
    const int*   kmer    = (const int*)  d_in[1];
    const int*   indices = (const int*)  d_in[2];
    const float* emb     = (const float*)d_in[3];
    const float* W1      = (const float*)d_in[4];
    const float* b1      = (const float*)d_in[5];
    const float* W2      = (const float*)d_in[6];
    const float* b2      = (const float*)d_in[7];
    const float* W3      = (const float*)d_in[8];
    const float* b3      = (const float*)d_in[9];
    const float* W4      = (const float*)d_in[10];
    const float* b4      = (const float*)d_in[11];

    float*  out = (float*)d_out;
    __bf16* h   = (__bf16*)d_ws;          // [N, 8] bf16 = 16 MB

    const int N = in_sizes[1];
    const int G = out_size;

    const int grid1 = (N + 1023) / 1024;  // 1024 reads / block (4 waves x 256)
    k_readmlp<<<grid1, 256, 0, stream>>>(x, kmer, emb, W1, b1, W2, b2, h, N);

    const int grid2 = (G + 31) / 32;
    k_site<<<grid2, 256, 0, stream>>>(h, indices, W3, b3, W4, b4, out, G);
}